// Round 2
// baseline (461.680 us; speedup 1.0000x reference)
//
#include <hip/hip_runtime.h>
#include <hip/hip_bf16.h>

typedef unsigned short u16;
typedef unsigned int u32;
typedef __attribute__((ext_vector_type(8))) short short8;
typedef __attribute__((ext_vector_type(4))) float f32x4;

#define NN 8192
#define KIN 256
#define FOUT 128
#define SPLITS 8
#define KPER (NN / SPLITS)   // 1024
#define BK 64
#define ITERS (KPER / BK)    // 16

__device__ __forceinline__ u16 f2bf(float f) {
    u32 u = __float_as_uint(f);
    u32 r = ((u >> 16) & 1u) + 0x7fffu;
    return (u16)((u + r) >> 16);
}
__device__ __forceinline__ u32 fkey(float f) {
    u32 b = __float_as_uint(f);
    return (b & 0x80000000u) ? ~b : (b | 0x80000000u);
}
__device__ __forceinline__ float funkey(u32 k) {
    u32 b = (k & 0x80000000u) ? (k & 0x7fffffffu) : ~k;
    return __uint_as_float(b);
}

// ---------------- K1: Wh = h@W (fp32 acc), Whbt (bf16 transposed), src/dst, gmax(dst)
__global__ __launch_bounds__(256) void k1_wh(
    const float* __restrict__ h, const float* __restrict__ W, const float* __restrict__ a,
    u16* __restrict__ whbt,
    float* __restrict__ src, float* __restrict__ dst, u32* __restrict__ gmaxk)
{
    __shared__ float hT[64][36];     // transposed h tile [k][r]
    __shared__ u16   lt[128][40];    // bf16 Wh^T tile [n][m], stride 40 u16 = 80B (16B mult)
    __shared__ float sd[32][2];      // per-row (src,dst) partials
    const int t  = threadIdx.x;
    const int m0 = blockIdx.x * 32;
    const int rq = t >> 5, cq = t & 31;

    float acc[4][4];
#pragma unroll
    for (int i = 0; i < 4; i++)
#pragma unroll
        for (int j = 0; j < 4; j++) acc[i][j] = 0.f;
    if (t < 64) sd[t >> 1][t & 1] = 0.f;

    for (int kt = 0; kt < KIN; kt += 64) {
        __syncthreads();
#pragma unroll
        for (int s2 = 0; s2 < 2; s2++) {
            int f = s2 * 256 + t;
            int r = f >> 4, kc = (f & 15) * 4;
            float4 hv = *(const float4*)(h + (size_t)(m0 + r) * KIN + kt + kc);
            hT[kc + 0][r] = hv.x; hT[kc + 1][r] = hv.y;
            hT[kc + 2][r] = hv.z; hT[kc + 3][r] = hv.w;
        }
        __syncthreads();
        for (int k = 0; k < 64; k++) {
            float4 wv = *(const float4*)(W + (size_t)(kt + k) * FOUT + cq * 4);
            float h0 = hT[k][rq * 4 + 0], h1 = hT[k][rq * 4 + 1];
            float h2 = hT[k][rq * 4 + 2], h3 = hT[k][rq * 4 + 3];
            acc[0][0] += h0 * wv.x; acc[0][1] += h0 * wv.y; acc[0][2] += h0 * wv.z; acc[0][3] += h0 * wv.w;
            acc[1][0] += h1 * wv.x; acc[1][1] += h1 * wv.y; acc[1][2] += h1 * wv.z; acc[1][3] += h1 * wv.w;
            acc[2][0] += h2 * wv.x; acc[2][1] += h2 * wv.y; acc[2][2] += h2 * wv.z; acc[2][3] += h2 * wv.w;
            acc[3][0] += h3 * wv.x; acc[3][1] += h3 * wv.y; acc[3][2] += h3 * wv.z; acc[3][3] += h3 * wv.w;
        }
    }
    // epilogue: bf16 transpose tile into LDS, src/dst partials
#pragma unroll
    for (int i = 0; i < 4; i++) {
        float sp = 0.f, dp = 0.f;
#pragma unroll
        for (int j = 0; j < 4; j++) {
            sp += acc[i][j] * a[cq * 4 + j];
            dp += acc[i][j] * a[FOUT + cq * 4 + j];
            lt[cq * 4 + j][rq * 4 + i] = f2bf(acc[i][j]);
        }
        atomicAdd(&sd[rq * 4 + i][0], sp);
        atomicAdd(&sd[rq * 4 + i][1], dp);
    }
    __syncthreads();
    if (t < 32) { src[m0 + t] = sd[t][0]; dst[m0 + t] = sd[t][1]; }
    if (t < 64) {
        float v = (t < 32) ? sd[t][1] : -3.0e38f;
#pragma unroll
        for (int off = 32; off >= 1; off >>= 1) v = fmaxf(v, __shfl_down(v, off));
        if (t == 0) atomicMax(gmaxk, fkey(v));
    }
    // coalesced bf16 transposed write: ALL 128 n-rows x 32 m-cols (512 uint4 = 2 per thread)
#pragma unroll
    for (int s2 = 0; s2 < 2; s2++) {
        int f = s2 * 256 + t;        // 0..511
        int n = f >> 2;              // 0..127
        int q = (f & 3) * 8;         // 0,8,16,24
        uint4 v = *(const uint4*)&lt[n][q];
        *(uint4*)(whbt + (size_t)n * NN + m0 + q) = v;
    }
}

// ---------------- K2: flash-style masked-softmax @ Wh with bf16 MFMA ----------------
__global__ __launch_bounds__(256) void k2_attn(
    const int* __restrict__ adj, const float* __restrict__ src, const float* __restrict__ dst,
    const u16* __restrict__ whbt, const u32* __restrict__ gmaxk,
    float* __restrict__ accp, float* __restrict__ lp)
{
    __shared__ u16 P[128][72];       // bf16 attention tile, +8 pad: frag reads <=2-way conflicts
    __shared__ float2 sC[128];       // (src_i, C_i)
    __shared__ float lred[128][16];
    const int t = threadIdx.x;
    const int i0 = blockIdx.x * 128;
    const int split = blockIdx.y;
    const int kb0 = split * KPER;
    const int lane = t & 63, wave = t >> 6;
    const int mw = (wave >> 1) * 64, nw = (wave & 1) * 64;
    const int l15 = lane & 15, quad = lane >> 4;
    const int g = t >> 4, c4 = (t & 15) * 4;

    if (t < 128) {
        float s = src[i0 + t];
        float gm = funkey(*gmaxk);
        float x = s + gm;
        sC[t] = make_float2(s, fmaxf(x, 0.01f * x));
    }
    float psum[8];
#pragma unroll
    for (int s2 = 0; s2 < 8; s2++) psum[s2] = 0.f;
    f32x4 acc[4][4];
#pragma unroll
    for (int mt = 0; mt < 4; mt++)
#pragma unroll
        for (int nt = 0; nt < 4; nt++) acc[mt][nt] = {0.f, 0.f, 0.f, 0.f};

    // prefetch iter 0 (adj rows: thread covers rows {16*s2+g}, cols c4..c4+3)
    int4 av[8]; float4 dv;
    dv = *(const float4*)(dst + kb0 + c4);
#pragma unroll
    for (int s2 = 0; s2 < 8; s2++)
        av[s2] = *(const int4*)(adj + (size_t)(i0 + 16 * s2 + g) * NN + kb0 + c4);

    for (int it = 0; it < ITERS; ++it) {
        const int kb = kb0 + it * BK;
        __syncthreads();             // (A) prev MFMA done with P; iter0: sC ready
        float4 d4 = dv;
#pragma unroll
        for (int s2 = 0; s2 < 8; s2++) {
            int r = 16 * s2 + g;
            float2 sc = sC[r];
            int4 a4 = av[s2];
            float x0 = sc.x + d4.x; x0 = fmaxf(x0, 0.01f * x0);
            float x1 = sc.x + d4.y; x1 = fmaxf(x1, 0.01f * x1);
            float x2 = sc.x + d4.z; x2 = fmaxf(x2, 0.01f * x2);
            float x3 = sc.x + d4.w; x3 = fmaxf(x3, 0.01f * x3);
            float p0 = (a4.x > 0) ? __expf(x0 - sc.y) : 0.f;
            float p1 = (a4.y > 0) ? __expf(x1 - sc.y) : 0.f;
            float p2 = (a4.z > 0) ? __expf(x2 - sc.y) : 0.f;
            float p3 = (a4.w > 0) ? __expf(x3 - sc.y) : 0.f;
            psum[s2] += (p0 + p1) + (p2 + p3);
            u32 lo = (u32)f2bf(p0) | ((u32)f2bf(p1) << 16);
            u32 hi = (u32)f2bf(p2) | ((u32)f2bf(p3) << 16);
            *(uint2*)&P[r][c4] = make_uint2(lo, hi);
        }
        __syncthreads();             // (B) P visible
        if (it + 1 < ITERS) {        // prefetch next adj tile under the MFMA
            int kbn = kb + BK;
            dv = *(const float4*)(dst + kbn + c4);
#pragma unroll
            for (int s2 = 0; s2 < 8; s2++)
                av[s2] = *(const int4*)(adj + (size_t)(i0 + 16 * s2 + g) * NN + kbn + c4);
        }
#pragma unroll
        for (int ks = 0; ks < 2; ks++) {
            int kk = ks * 32 + quad * 8;
            short8 af[4], bfr[4];
#pragma unroll
            for (int mt = 0; mt < 4; mt++)
                af[mt] = *(const short8*)&P[mw + mt * 16 + l15][kk];
#pragma unroll
            for (int nt = 0; nt < 4; nt++) {
                int n = nw + nt * 16 + l15;
                bfr[nt] = *(const short8*)(whbt + (size_t)n * NN + kb + kk);
            }
#pragma unroll
            for (int mt = 0; mt < 4; mt++)
#pragma unroll
                for (int nt = 0; nt < 4; nt++)
                    acc[mt][nt] = __builtin_amdgcn_mfma_f32_16x16x32_bf16(
                        af[mt], bfr[nt], acc[mt][nt], 0, 0, 0);
        }
    }
    // row-sum partials
    __syncthreads();
#pragma unroll
    for (int s2 = 0; s2 < 8; s2++) lred[16 * s2 + g][t & 15] = psum[s2];
    __syncthreads();
    if (t < 128) {
        float s = 0.f;
#pragma unroll
        for (int j = 0; j < 16; j++) s += lred[t][j];
        lp[split * NN + i0 + t] = s;
    }
    // accumulator partials (C/D layout: col=lane&15, row=quad*4+reg)
    float* ab = accp + (size_t)split * (NN * FOUT);
#pragma unroll
    for (int mt = 0; mt < 4; mt++)
#pragma unroll
        for (int nt = 0; nt < 4; nt++) {
            int row = i0 + mw + mt * 16 + quad * 4;
            int col = nw + nt * 16 + l15;
#pragma unroll
            for (int reg = 0; reg < 4; reg++)
                ab[(size_t)(row + reg) * FOUT + col] = acc[mt][nt][reg];
        }
}

// ---------------- K3: combine splits, divide by row sums ---------------------------
__global__ __launch_bounds__(256) void k3_comb(
    const float* __restrict__ accp, const float* __restrict__ lp, float* __restrict__ out)
{
    int idx = blockIdx.x * 256 + threadIdx.x;   // float4 index, 0..262143
    int i = idx >> 5;                           // row
    float4 s = make_float4(0.f, 0.f, 0.f, 0.f);
    float l = 0.f;
#pragma unroll
    for (int sp = 0; sp < SPLITS; sp++) {
        float4 v = *(const float4*)(accp + (size_t)sp * (NN * FOUT) + (size_t)idx * 4);
        s.x += v.x; s.y += v.y; s.z += v.z; s.w += v.w;
        l += lp[sp * NN + i];
    }
    float inv = 1.0f / l;
    *(float4*)(out + (size_t)idx * 4) = make_float4(s.x * inv, s.y * inv, s.z * inv, s.w * inv);
}

extern "C" void kernel_launch(void* const* d_in, const int* in_sizes, int n_in,
                              void* d_out, int out_size, void* d_ws, size_t ws_size,
                              hipStream_t stream) {
    const float* h   = (const float*)d_in[0];
    const int*   adj = (const int*)d_in[1];
    const float* W   = (const float*)d_in[2];
    const float* a   = (const float*)d_in[3];
    float* out = (float*)d_out;

    char* ws = (char*)d_ws;
    u16*   whbt  = (u16*)ws;                            // 2 MB
    float* src   = (float*)(ws + (2u << 20));           // 32 KB
    float* dst   = src + NN;                            // 32 KB
    u32*   gmaxk = (u32*)(dst + NN);                    // 4 B
    float* accp  = (float*)(ws + (3u << 20));           // 32 MB
    float* lp    = (float*)(ws + (35u << 20));          // 256 KB

    hipMemsetAsync(gmaxk, 0, sizeof(u32), stream);
    k1_wh<<<dim3(NN / 32), dim3(256), 0, stream>>>(h, W, a, whbt, src, dst, gmaxk);
    k2_attn<<<dim3(NN / 128, SPLITS), dim3(256), 0, stream>>>(adj, src, dst, whbt, gmaxk, accp, lp);
    k3_comb<<<dim3((NN * FOUT / 4) / 256), dim3(256), 0, stream>>>(accp, lp, out);
}